// Round 1
// baseline (157.491 us; speedup 1.0000x reference)
//
#include <hip/hip_runtime.h>
#include <math.h>

#define L 2048
#define LMASK (L - 1)
#define NCELL (L * L)
#define H 64

// ---------------- Kernel 1: sum(state) ----------------
__global__ void reduce_sum_kernel(const int* __restrict__ state,
                                  int* __restrict__ sum) {
    int idx = blockIdx.x * blockDim.x + threadIdx.x;
    const int4* s4 = (const int4*)state;
    int4 v = s4[idx];                       // grid exactly covers NCELL/4
    int x = v.x + v.y + v.z + v.w;
    #pragma unroll
    for (int off = 32; off > 0; off >>= 1)
        x += __shfl_down(x, off, 64);
    __shared__ int ls[4];                   // 256 threads / wave64 = 4 waves
    int lane = threadIdx.x & 63;
    int wave = threadIdx.x >> 6;
    if (lane == 0) ls[wave] = x;
    __syncthreads();
    if (threadIdx.x == 0) {
        atomicAdd(sum, ls[0] + ls[1] + ls[2] + ls[3]);
    }
}

// ---------------- Kernel 2: 12-combo MLP table ----------------
// table[b*4 + {0,1,2}] = {p0, p1, value} for combo b = s*6 + nc
__global__ void mlp_table_kernel(const float* __restrict__ W1,
                                 const float* __restrict__ b1,
                                 const float* __restrict__ W2,
                                 const float* __restrict__ b2,
                                 const float* __restrict__ Wa,
                                 const float* __restrict__ ba,
                                 const float* __restrict__ Wc,
                                 const float* __restrict__ bc,
                                 const int* __restrict__ sum,
                                 float* __restrict__ table) {
    __shared__ float h1[H];
    __shared__ float h2[H];
    int b = blockIdx.x;                     // 0..11
    int j = threadIdx.x;                    // 0..63
    float f0 = (float)(b / 6);              // state
    float f1 = (float)(b % 6);              // neighbor_coop
    float f2 = (float)(*sum) * (1.0f / (float)NCELL);  // global_coop

    float a = W1[0 * H + j] * f0 + W1[1 * H + j] * f1 + W1[2 * H + j] * f2 + b1[j];
    h1[j] = fmaxf(a, 0.0f);
    __syncthreads();

    float acc = b2[j];
    #pragma unroll
    for (int k = 0; k < H; ++k) acc += h1[k] * W2[k * H + j];
    h2[j] = fmaxf(acc, 0.0f);
    __syncthreads();

    if (j == 0) {
        float la = ba[0], lb = ba[1], v = bc[0];
        #pragma unroll
        for (int k = 0; k < H; ++k) {
            la += h2[k] * Wa[k * 2 + 0];
            lb += h2[k] * Wa[k * 2 + 1];
            v  += h2[k] * Wc[k];
        }
        float m = fmaxf(la, lb);
        float e0 = expf(la - m), e1 = expf(lb - m);
        float inv = 1.0f / (e0 + e1);
        table[b * 4 + 0] = e0 * inv;
        table[b * 4 + 1] = e1 * inv;
        table[b * 4 + 2] = v;
    }
}

// ---------------- Kernel 3: per-cell stencil + lookup + store ----------------
// reward stencil (exact, R=5): t = 6*c + 3*(n+s+e+w) + 2*(diag) + 1*(2-away axis)
// reward = t - 6*c_if_cooperator  -> reward = t - 6*c  (c in {0,1})
__global__ void cell_kernel(const int* __restrict__ state,
                            const float* __restrict__ table,
                            float* __restrict__ out) {
    __shared__ float tbl[48];
    if (threadIdx.x < 48) tbl[threadIdx.x] = table[threadIdx.x];
    __syncthreads();

    int idx = blockIdx.x * blockDim.x + threadIdx.x;
    int i = idx >> 11;
    int j = idx & LMASK;
    int im1 = (i - 1) & LMASK, ip1 = (i + 1) & LMASK;
    int im2 = (i - 2) & LMASK, ip2 = (i + 2) & LMASK;
    int jm1 = (j - 1) & LMASK, jp1 = (j + 1) & LMASK;
    int jm2 = (j - 2) & LMASK, jp2 = (j + 2) & LMASK;

    const int* r0 = state + i * L;
    const int* rn = state + im1 * L;
    const int* rs = state + ip1 * L;

    int c  = r0[j];
    int w  = r0[jm1];
    int e  = r0[jp1];
    int ww = r0[jm2];
    int ee = r0[jp2];
    int n  = rn[j];
    int nw = rn[jm1];
    int ne = rn[jp1];
    int s  = rs[j];
    int sw = rs[jm1];
    int se = rs[jp1];
    int nn = state[im2 * L + j];
    int ss = state[ip2 * L + j];

    int nc = c + n + s + e + w;
    int t  = 6 * c + 3 * (n + s + e + w) + 2 * (ne + nw + se + sw)
             + (nn + ss + ee + ww);
    float reward = (float)(t - 6 * c);

    int combo = c * 6 + nc;
    float2 p;
    p.x = tbl[combo * 4 + 0];
    p.y = tbl[combo * 4 + 1];
    float val = tbl[combo * 4 + 2];

    ((float2*)out)[idx]      = p;        // action_probs [NCELL,2]
    out[2 * NCELL + idx]     = val;      // state_value  [NCELL]
    out[3 * NCELL + idx]     = reward;   // reward       [NCELL]
}

extern "C" void kernel_launch(void* const* d_in, const int* in_sizes, int n_in,
                              void* d_out, int out_size, void* d_ws, size_t ws_size,
                              hipStream_t stream) {
    const int*   state = (const int*)d_in[0];
    const float* W1 = (const float*)d_in[1];
    const float* b1 = (const float*)d_in[2];
    const float* W2 = (const float*)d_in[3];
    const float* b2 = (const float*)d_in[4];
    const float* Wa = (const float*)d_in[5];
    const float* ba = (const float*)d_in[6];
    const float* Wc = (const float*)d_in[7];
    const float* bc = (const float*)d_in[8];
    float* out = (float*)d_out;

    int*   sum   = (int*)d_ws;
    float* table = (float*)((char*)d_ws + 64);

    hipMemsetAsync(d_ws, 0, 64, stream);   // zero the accumulator (ws is poisoned)

    reduce_sum_kernel<<<NCELL / 4 / 256, 256, 0, stream>>>(state, sum);
    mlp_table_kernel<<<12, 64, 0, stream>>>(W1, b1, W2, b2, Wa, ba, Wc, bc,
                                            sum, table);
    cell_kernel<<<NCELL / 256, 256, 0, stream>>>(state, table, out);
}

// Round 2
// 116.388 us; speedup vs baseline: 1.3532x; 1.3532x over previous
//
#include <hip/hip_runtime.h>
#include <math.h>

#define L 2048
#define LMASK (L - 1)
#define LB 512            // int4-blocks per row
#define LBMASK (LB - 1)
#define NCELL (L * L)
#define H 64

#define RED_BLOCKS 256
#define RED_THREADS 256
#define RED_ITERS (NCELL / 4 / (RED_BLOCKS * RED_THREADS))   // 16

// ---------------- Kernel 1: per-block partial sums (NO atomics) ----------------
__global__ void reduce_sum_kernel(const int* __restrict__ state,
                                  int* __restrict__ partials) {
    const int4* s4 = (const int4*)state;
    int tid = blockIdx.x * blockDim.x + threadIdx.x;
    int x = 0;
    #pragma unroll
    for (int k = 0; k < RED_ITERS; ++k) {
        int4 v = s4[tid + k * (RED_BLOCKS * RED_THREADS)];
        x += v.x + v.y + v.z + v.w;
    }
    #pragma unroll
    for (int off = 32; off > 0; off >>= 1)
        x += __shfl_down(x, off, 64);
    __shared__ int ls[4];
    if ((threadIdx.x & 63) == 0) ls[threadIdx.x >> 6] = x;
    __syncthreads();
    if (threadIdx.x == 0)
        partials[blockIdx.x] = ls[0] + ls[1] + ls[2] + ls[3];
}

// ---------------- Kernel 2: 12-combo MLP table ----------------
// table[b*4 + {0,1,2}] = {p0, p1, value} for combo b = s*6 + nc
__global__ void mlp_table_kernel(const float* __restrict__ W1,
                                 const float* __restrict__ b1,
                                 const float* __restrict__ W2,
                                 const float* __restrict__ b2,
                                 const float* __restrict__ Wa,
                                 const float* __restrict__ ba,
                                 const float* __restrict__ Wc,
                                 const float* __restrict__ bc,
                                 const int* __restrict__ partials,
                                 float* __restrict__ table) {
    __shared__ float h1[H];
    __shared__ float h2[H];
    int b = blockIdx.x;                     // 0..11
    int j = threadIdx.x;                    // 0..63

    // each block redundantly reduces the 256 partials (one wave, trivial)
    int sum = partials[j] + partials[j + 64] + partials[j + 128] + partials[j + 192];
    #pragma unroll
    for (int off = 32; off > 0; off >>= 1)
        sum += __shfl_xor(sum, off, 64);

    float f0 = (float)(b / 6);              // state
    float f1 = (float)(b % 6);              // neighbor_coop
    float f2 = (float)sum * (1.0f / (float)NCELL);  // global_coop

    float a = W1[0 * H + j] * f0 + W1[1 * H + j] * f1 + W1[2 * H + j] * f2 + b1[j];
    h1[j] = fmaxf(a, 0.0f);
    __syncthreads();

    float acc = b2[j];
    #pragma unroll
    for (int k = 0; k < H; ++k) acc += h1[k] * W2[k * H + j];
    h2[j] = fmaxf(acc, 0.0f);
    __syncthreads();

    if (j == 0) {
        float la = ba[0], lb = ba[1], v = bc[0];
        #pragma unroll
        for (int k = 0; k < H; ++k) {
            la += h2[k] * Wa[k * 2 + 0];
            lb += h2[k] * Wa[k * 2 + 1];
            v  += h2[k] * Wc[k];
        }
        float m = fmaxf(la, lb);
        float e0 = expf(la - m), e1 = expf(lb - m);
        float inv = 1.0f / (e0 + e1);
        table[b * 4 + 0] = e0 * inv;
        table[b * 4 + 1] = e1 * inv;
        table[b * 4 + 2] = v;
    }
}

// ---------------- Kernel 3: 4 cells/thread, int4 loads, float4 stores ----------
// reward = 3*(n+s+e+w) + 2*(ne+nw+se+sw) + (nn+ss+ee+ww)   [center cancels]
__global__ void cell_kernel(const int* __restrict__ state,
                            const float* __restrict__ table,
                            float* __restrict__ out) {
    __shared__ float tbl[48];
    if (threadIdx.x < 48) tbl[threadIdx.x] = table[threadIdx.x];
    __syncthreads();

    int tid = blockIdx.x * blockDim.x + threadIdx.x;   // 0 .. NCELL/4-1
    int i  = tid >> 9;          // row
    int jb = tid & LBMASK;      // int4-block in row
    int im1 = (i - 1) & LMASK, ip1 = (i + 1) & LMASK;
    int im2 = (i - 2) & LMASK, ip2 = (i + 2) & LMASK;
    int jbm1 = (jb - 1) & LBMASK, jbp1 = (jb + 1) & LBMASK;

    const int4* s4 = (const int4*)state;
    int4 m0 = s4[i   * LB + jbm1], m1 = s4[i   * LB + jb], m2 = s4[i   * LB + jbp1];
    int4 n0 = s4[im1 * LB + jbm1], n1 = s4[im1 * LB + jb], n2 = s4[im1 * LB + jbp1];
    int4 q0 = s4[ip1 * LB + jbm1], q1 = s4[ip1 * LB + jb], q2 = s4[ip1 * LB + jbp1];
    int4 uu4 = s4[im2 * LB + jb];
    int4 dd4 = s4[ip2 * LB + jb];

    int m [12] = {m0.x,m0.y,m0.z,m0.w, m1.x,m1.y,m1.z,m1.w, m2.x,m2.y,m2.z,m2.w};
    int nr[12] = {n0.x,n0.y,n0.z,n0.w, n1.x,n1.y,n1.z,n1.w, n2.x,n2.y,n2.z,n2.w};
    int sr[12] = {q0.x,q0.y,q0.z,q0.w, q1.x,q1.y,q1.z,q1.w, q2.x,q2.y,q2.z,q2.w};
    int ur[4]  = {uu4.x,uu4.y,uu4.z,uu4.w};
    int dr[4]  = {dd4.x,dd4.y,dd4.z,dd4.w};

    float pr[8], vv[4], rw[4];
    #pragma unroll
    for (int t = 0; t < 4; ++t) {
        int c  = m[4 + t],  w  = m[3 + t],  e  = m[5 + t];
        int ww = m[2 + t],  ee = m[6 + t];
        int n  = nr[4 + t], nw = nr[3 + t], ne = nr[5 + t];
        int s  = sr[4 + t], sw = sr[3 + t], se = sr[5 + t];
        int nn = ur[t],     ss = dr[t];

        int axis1 = n + s + e + w;
        rw[t] = (float)(3 * axis1 + 2 * (nw + ne + sw + se) + (nn + ss + ww + ee));

        int combo = c * 6 + (c + axis1);
        pr[2 * t]     = tbl[combo * 4 + 0];
        pr[2 * t + 1] = tbl[combo * 4 + 1];
        vv[t]         = tbl[combo * 4 + 2];
    }

    float4* o4 = (float4*)out;
    o4[tid * 2]     = make_float4(pr[0], pr[1], pr[2], pr[3]);
    o4[tid * 2 + 1] = make_float4(pr[4], pr[5], pr[6], pr[7]);
    ((float4*)(out + 2 * (size_t)NCELL))[tid] = make_float4(vv[0], vv[1], vv[2], vv[3]);
    ((float4*)(out + 3 * (size_t)NCELL))[tid] = make_float4(rw[0], rw[1], rw[2], rw[3]);
}

extern "C" void kernel_launch(void* const* d_in, const int* in_sizes, int n_in,
                              void* d_out, int out_size, void* d_ws, size_t ws_size,
                              hipStream_t stream) {
    const int*   state = (const int*)d_in[0];
    const float* W1 = (const float*)d_in[1];
    const float* b1 = (const float*)d_in[2];
    const float* W2 = (const float*)d_in[3];
    const float* b2 = (const float*)d_in[4];
    const float* Wa = (const float*)d_in[5];
    const float* ba = (const float*)d_in[6];
    const float* Wc = (const float*)d_in[7];
    const float* bc = (const float*)d_in[8];
    float* out = (float*)d_out;

    int*   partials = (int*)d_ws;                         // 256 ints
    float* table    = (float*)((char*)d_ws + 1024);       // 48 floats

    reduce_sum_kernel<<<RED_BLOCKS, RED_THREADS, 0, stream>>>(state, partials);
    mlp_table_kernel<<<12, 64, 0, stream>>>(W1, b1, W2, b2, Wa, ba, Wc, bc,
                                            partials, table);
    cell_kernel<<<NCELL / 4 / 256, 256, 0, stream>>>(state, table, out);
}